// Round 1
// baseline (207.886 us; speedup 1.0000x reference)
//
#include <hip/hip_runtime.h>
#include <hip/hip_bf16.h>

// Problem constants (match reference.py)
#define BB 64
#define SS 512
#define WW 400
#define DD 1024
#define D4 (DD / 4)   // 256 float4 per row

// One block per (b, w). 256 threads; thread t owns float4 #t of the D dim.
__global__ __launch_bounds__(256) void bert_span_mean(
    const float* __restrict__ emb,     // [B, S, D]
    const int*   __restrict__ offs,    // [B, W, 2]
    const int*   __restrict__ mask,    // [B, W]
    float*       __restrict__ out)     // [B, W, D]
{
    const int bw = blockIdx.x;           // 0 .. B*W-1 (block-uniform)
    const int b  = bw / WW;

    const int st = offs[2 * bw];
    const int ed = offs[2 * bw + 1];
    const int m  = mask[bw];

    const int t = threadIdx.x;           // 0..255 -> float4 lane in D

    float4 acc = make_float4(0.f, 0.f, 0.f, 0.f);

    const bool valid = (m != 0) && (ed > st);
    if (valid) {
        const float4* src = reinterpret_cast<const float4*>(
            emb + (size_t)b * SS * DD) + t;
        for (int s = st; s < ed; ++s) {
            float4 v = src[(size_t)s * D4];
            acc.x += v.x; acc.y += v.y; acc.z += v.z; acc.w += v.w;
        }
        const float inv = 1.0f / (float)(ed - st);
        acc.x *= inv; acc.y *= inv; acc.z *= inv; acc.w *= inv;
    }

    reinterpret_cast<float4*>(out)[(size_t)bw * D4 + t] = acc;
}

extern "C" void kernel_launch(void* const* d_in, const int* in_sizes, int n_in,
                              void* d_out, int out_size, void* d_ws, size_t ws_size,
                              hipStream_t stream) {
    const float* emb  = (const float*)d_in[0];
    const int*   offs = (const int*)d_in[1];
    const int*   mask = (const int*)d_in[2];
    float*       out  = (float*)d_out;

    const int nblocks = BB * WW;  // 25600
    bert_span_mean<<<nblocks, 256, 0, stream>>>(emb, offs, mask, out);
}